// Round 1
// baseline (1887.952 us; speedup 1.0000x reference)
//
#include <hip/hip_runtime.h>
#include <hip/hip_bf16.h>
#include <math.h>

// Problem constants
#define BB 8
#define SS 512
#define DD 768
#define LL 200

// ---------------------------------------------------------------------------
// Generic tiled fp32 GEMM: C[M,N] = epi(A[M,K] @ op(B) + bias)
// EPI: 0=none, 1=leaky(0.2), 2=sigmoid.  TB: B is [N,K] (use B^T).
// ---------------------------------------------------------------------------
#define BM 64
#define BN 64
#define BKK 16

template<int EPI, bool TB>
__global__ __launch_bounds__(256) void gemm_k(
    const float* __restrict__ A, int lda,
    const float* __restrict__ B, int ldb,
    const float* __restrict__ bias,
    float* __restrict__ C, int ldc,
    int M, int N, int K)
{
    __shared__ float As[BKK][BM + 4];
    __shared__ float Bs[BKK][BN + 4];
    const int tid = threadIdx.x;
    const int bm = blockIdx.y * BM;
    const int bn = blockIdx.x * BN;
    const int tx = tid & 15;   // -> 4 cols
    const int ty = tid >> 4;   // -> 4 rows

    float acc[4][4] = {};

    for (int k0 = 0; k0 < K; k0 += BKK) {
        // A tile: As[kk][m]
        for (int idx = tid; idx < BM * BKK; idx += 256) {
            int m = idx >> 4, kk = idx & 15;
            int gm = bm + m, gk = k0 + kk;
            float v = 0.f;
            if (gm < M && gk < K) v = A[(size_t)gm * lda + gk];
            As[kk][m] = v;
        }
        // B tile: Bs[kk][n]
        if (!TB) {
            for (int idx = tid; idx < BKK * BN; idx += 256) {
                int kk = idx >> 6, n = idx & 63;
                int gn = bn + n, gk = k0 + kk;
                float v = 0.f;
                if (gn < N && gk < K) v = B[(size_t)gk * ldb + gn];
                Bs[kk][n] = v;
            }
        } else {
            for (int idx = tid; idx < BKK * BN; idx += 256) {
                int n = idx >> 4, kk = idx & 15;
                int gn = bn + n, gk = k0 + kk;
                float v = 0.f;
                if (gn < N && gk < K) v = B[(size_t)gn * ldb + gk];
                Bs[kk][n] = v;
            }
        }
        __syncthreads();
        #pragma unroll
        for (int kk = 0; kk < BKK; ++kk) {
            float a[4], bb[4];
            #pragma unroll
            for (int i = 0; i < 4; ++i) a[i] = As[kk][ty * 4 + i];
            #pragma unroll
            for (int j = 0; j < 4; ++j) bb[j] = Bs[kk][tx * 4 + j];
            #pragma unroll
            for (int i = 0; i < 4; ++i)
                #pragma unroll
                for (int j = 0; j < 4; ++j)
                    acc[i][j] = fmaf(a[i], bb[j], acc[i][j]);
        }
        __syncthreads();
    }

    #pragma unroll
    for (int i = 0; i < 4; ++i) {
        int gm = bm + ty * 4 + i;
        if (gm >= M) continue;
        #pragma unroll
        for (int j = 0; j < 4; ++j) {
            int gn = bn + tx * 4 + j;
            if (gn >= N) continue;
            float v = acc[i][j];
            if (bias) v += bias[gn];
            if (EPI == 1) v = (v >= 0.f) ? v : 0.2f * v;
            else if (EPI == 2) v = 1.f / (1.f + expf(-v));
            C[(size_t)gm * ldc + gn] = v;
        }
    }
}

// d[m] = rsqrt(sum_l A[l,m]) (column sums of A [L,L])
__global__ void colsum_rsqrt_k(const float* __restrict__ A, float* __restrict__ d)
{
    int m = blockIdx.x * blockDim.x + threadIdx.x;
    if (m < LL) {
        float s = 0.f;
        for (int l = 0; l < LL; ++l) s += A[l * LL + m];
        d[m] = (s > 0.f) ? (1.f / sqrtf(s)) : 0.f;
    }
}

// A_norm[i,j] = A[j,i] * d[i] * d[j]
__global__ void anorm_k(const float* __restrict__ A, const float* __restrict__ d,
                        float* __restrict__ An)
{
    int idx = blockIdx.x * blockDim.x + threadIdx.x;
    if (idx < LL * LL) {
        int i = idx / LL, j = idx % LL;
        An[idx] = A[j * LL + i] * d[i] * d[j];
    }
}

// l1-normalize columns of X [L, D] in place (axis = L)
__global__ void l1norm_cols_k(float* __restrict__ X)
{
    int dcol = blockIdx.x * blockDim.x + threadIdx.x;
    if (dcol < DD) {
        float s = 0.f;
        for (int l = 0; l < LL; ++l) s += fabsf(X[l * DD + dcol]);
        float inv = 1.f / fmaxf(s, 1e-12f);
        for (int l = 0; l < LL; ++l) X[l * DD + dcol] *= inv;
    }
}

// doc_n[b,s,d] = doc[b,s,d] / max(sum_s |doc[b,s,d]|, 1e-12)
__global__ void doc_l1norm_k(const float* __restrict__ doc, float* __restrict__ out)
{
    int idx = blockIdx.x * blockDim.x + threadIdx.x;  // b*DD + d
    if (idx >= BB * DD) return;
    int b = idx / DD, dcol = idx % DD;
    const float* p = doc + (size_t)b * SS * DD + dcol;
    float s = 0.f;
    for (int t = 0; t < SS; ++t) s += fabsf(p[(size_t)t * DD]);
    float inv = 1.f / fmaxf(s, 1e-12f);
    float* q = out + (size_t)b * SS * DD + dcol;
    for (int t = 0; t < SS; ++t) q[(size_t)t * DD] = p[(size_t)t * DD] * inv;
}

// Fused conv(9x9, 200ch) -> +bias -> max over (channel, width) -> tanh, per (b,s)
__global__ __launch_bounds__(256) void conv_max_k(
    const float* __restrict__ wla,   // [B*S, L]
    const float* __restrict__ cw,    // [L, 81]
    const float* __restrict__ cb,    // [L]
    float* __restrict__ gate)        // [B*S]
{
    const int bs = blockIdx.x;          // 0..B*S-1
    const int b = bs >> 9;              // /512
    const int s = bs & 511;
    __shared__ float win[9][208];       // rows s-4..s+4, cols -4..203
    const int tid = threadIdx.x;

    for (int idx = tid; idx < 9 * 208; idx += 256) {
        int i = idx / 208, c = idx % 208;
        int row = s - 4 + i;
        int col = c - 4;
        float v = 0.f;
        if (row >= 0 && row < SS && col >= 0 && col < LL)
            v = wla[((size_t)b * SS + row) * LL + col];
        win[i][c] = v;
    }
    __syncthreads();

    const int l = tid;
    float p[81];
    if (l < LL) {
        #pragma unroll
        for (int i = 0; i < 9; ++i)
            #pragma unroll
            for (int j = 0; j < 9; ++j)
                p[i * 9 + j] = win[i][l + j];
    } else {
        #pragma unroll
        for (int t = 0; t < 81; ++t) p[t] = 0.f;
    }

    float m = -INFINITY;
    #pragma unroll 2
    for (int o = 0; o < LL; ++o) {
        const float* w = cw + o * 81;   // uniform address -> scalar loads
        float acc = cb[o];
        #pragma unroll
        for (int t = 0; t < 81; ++t) acc = fmaf(p[t], w[t], acc);
        m = fmaxf(m, acc);
    }
    if (l >= LL) m = -INFINITY;

    // block max reduce
    #pragma unroll
    for (int off = 32; off > 0; off >>= 1) m = fmaxf(m, __shfl_down(m, off, 64));
    __shared__ float wmax[4];
    if ((tid & 63) == 0) wmax[tid >> 6] = m;
    __syncthreads();
    if (tid == 0) {
        float mm = fmaxf(fmaxf(wmax[0], wmax[1]), fmaxf(wmax[2], wmax[3]));
        gate[bs] = tanhf(mm);
    }
}

// h[b,d] = sum_s gate[b,s] * doc_n[b,s,d]
__global__ void henc_k(const float* __restrict__ doc_n, const float* __restrict__ gate,
                       float* __restrict__ h)
{
    int idx = blockIdx.x * blockDim.x + threadIdx.x;  // b*DD + d
    if (idx >= BB * DD) return;
    int b = idx / DD, dcol = idx % DD;
    const float* p = doc_n + (size_t)b * SS * DD + dcol;
    const float* g = gate + b * SS;
    float s = 0.f;
    for (int t = 0; t < SS; ++t) s = fmaf(p[(size_t)t * DD], g[t], s);
    h[idx] = s;
}

// out[b,l] = sigmoid(h[b,:] @ W[:,l] + bias[l])
__global__ void final_k(const float* __restrict__ h, const float* __restrict__ W,
                        const float* __restrict__ bias, float* __restrict__ out)
{
    int b = blockIdx.x;
    int l = threadIdx.x;
    if (l < LL) {
        const float* hb = h + b * DD;
        float acc = bias[l];
        for (int d = 0; d < DD; ++d) acc = fmaf(hb[d], W[d * LL + l], acc);
        out[b * LL + l] = 1.f / (1.f + expf(-acc));
    }
}

// loss = -mean(y*log(p) + (1-y)*log(1-p)), p clipped to [1e-7, 1-1e-7]
__global__ void loss_k(const float* __restrict__ out, const float* __restrict__ labels,
                       float* __restrict__ loss_out)
{
    float s = 0.f;
    for (int i = threadIdx.x; i < BB * LL; i += 256) {
        float p = out[i];
        p = fminf(fmaxf(p, 1e-7f), 1.f - 1e-7f);
        float y = labels[i];
        s += y * logf(p) + (1.f - y) * logf(1.f - p);
    }
    #pragma unroll
    for (int off = 32; off > 0; off >>= 1) s += __shfl_down(s, off, 64);
    __shared__ float ws[4];
    if ((threadIdx.x & 63) == 0) ws[threadIdx.x >> 6] = s;
    __syncthreads();
    if (threadIdx.x == 0)
        loss_out[0] = -(ws[0] + ws[1] + ws[2] + ws[3]) / (float)(BB * LL);
}

// ---------------------------------------------------------------------------
static void gemm(hipStream_t st, int epi, bool tb,
                 const float* A, int lda, const float* B, int ldb,
                 const float* bias, float* C, int ldc, int M, int N, int K)
{
    dim3 g((N + BN - 1) / BN, (M + BM - 1) / BM);
    if (!tb) {
        if (epi == 0)      gemm_k<0, false><<<g, 256, 0, st>>>(A, lda, B, ldb, bias, C, ldc, M, N, K);
        else if (epi == 1) gemm_k<1, false><<<g, 256, 0, st>>>(A, lda, B, ldb, bias, C, ldc, M, N, K);
        else               gemm_k<2, false><<<g, 256, 0, st>>>(A, lda, B, ldb, bias, C, ldc, M, N, K);
    } else {
        if (epi == 0)      gemm_k<0, true><<<g, 256, 0, st>>>(A, lda, B, ldb, bias, C, ldc, M, N, K);
        else if (epi == 1) gemm_k<1, true><<<g, 256, 0, st>>>(A, lda, B, ldb, bias, C, ldc, M, N, K);
        else               gemm_k<2, true><<<g, 256, 0, st>>>(A, lda, B, ldb, bias, C, ldc, M, N, K);
    }
}

extern "C" void kernel_launch(void* const* d_in, const int* in_sizes, int n_in,
                              void* d_out, int out_size, void* d_ws, size_t ws_size,
                              hipStream_t stream)
{
    const float* doc_emb   = (const float*)d_in[0];   // [B,S,D]
    const float* labels    = (const float*)d_in[1];   // [B,L]
    const float* label_emb = (const float*)d_in[2];   // [L,D]
    const float* label_adj = (const float*)d_in[3];   // [L,L]
    const float* w_gcn3    = (const float*)d_in[4];   // [D,D]
    const float* w_gcn5    = (const float*)d_in[5];   // [D,D]
    const float* w_ll1     = (const float*)d_in[6];   // [D,D]
    const float* b_ll1     = (const float*)d_in[7];   // [D]
    const float* w_ll2     = (const float*)d_in[8];   // [D,D]
    const float* b_ll2     = (const float*)d_in[9];   // [D]
    const float* w_lin     = (const float*)d_in[10];  // [2D,D]
    const float* b_lin     = (const float*)d_in[11];  // [D]
    const float* conv_w    = (const float*)d_in[12];  // [L,1,9,9]
    const float* conv_b    = (const float*)d_in[13];  // [L]
    const float* w_lin1    = (const float*)d_in[14];  // [D,L]
    const float* b_lin1    = (const float*)d_in[15];  // [L]

    float* out = (float*)d_out;                       // [B*L] + [1]
    float* ws  = (float*)d_ws;

    // workspace layout (floats)
    float* le_cat = ws;                        // [L, 2D] (le | d_le)
    float* tmp    = le_cat + LL * 2 * DD;      // [L, D]
    float* q      = tmp + LL * DD;             // [L, D]
    float* k      = q + LL * DD;               // [L, D]
    float* Amat   = k + LL * DD;               // [L, L]
    float* dvec   = Amat + LL * LL;            // [256]
    float* Anorm  = dvec + 256;                // [L, L]
    float* le_out = Anorm + LL * LL;           // [L, D]
    float* doc_n  = le_out + LL * DD;          // [B, S, D]
    float* wla    = doc_n + (size_t)BB * SS * DD;  // [B*S, L]
    float* gatev  = wla + (size_t)BB * SS * LL;    // [B*S]
    float* h_enc  = gatev + BB * SS;           // [B, D]

    // 1. tmp = label_emb @ w_gcn3
    gemm(stream, 0, false, label_emb, DD, w_gcn3, DD, nullptr, tmp, DD, LL, DD, DD);
    // 2. le = leaky(label_adj @ tmp)  -> le_cat[:, :D]
    gemm(stream, 1, false, label_adj, LL, tmp, DD, nullptr, le_cat, 2 * DD, LL, DD, LL);
    // 3. q = le @ w_ll1 + b_ll1
    gemm(stream, 0, false, le_cat, 2 * DD, w_ll1, DD, b_ll1, q, DD, LL, DD, DD);
    // 4. k = le @ w_ll2 + b_ll2
    gemm(stream, 0, false, le_cat, 2 * DD, w_ll2, DD, b_ll2, k, DD, LL, DD, DD);
    // 5. A = sigmoid(q @ k^T)
    gemm(stream, 2, true, q, DD, k, DD, nullptr, Amat, LL, LL, LL, DD);
    // 6. d = rsqrt(colsum(A))
    colsum_rsqrt_k<<<1, 256, 0, stream>>>(Amat, dvec);
    // 7. A_norm[i,j] = A[j,i]*d[i]*d[j]
    anorm_k<<<(LL * LL + 255) / 256, 256, 0, stream>>>(Amat, dvec, Anorm);
    // 8. tmp = le @ w_gcn5
    gemm(stream, 0, false, le_cat, 2 * DD, w_gcn5, DD, nullptr, tmp, DD, LL, DD, DD);
    // 9. d_le = leaky(A_norm @ tmp) -> le_cat[:, D:]
    gemm(stream, 1, false, Anorm, LL, tmp, DD, nullptr, le_cat + DD, 2 * DD, LL, DD, LL);
    // 10. le_out = le_cat @ w_lin + b_lin
    gemm(stream, 0, false, le_cat, 2 * DD, w_lin, DD, b_lin, le_out, DD, LL, DD, 2 * DD);
    // 11. l1 normalize le_out over L (columns)
    l1norm_cols_k<<<(DD + 255) / 256, 256, 0, stream>>>(le_out);
    // 12. doc l1 normalize over S
    doc_l1norm_k<<<(BB * DD + 255) / 256, 256, 0, stream>>>(doc_emb, doc_n);
    // 13. wla = doc_n @ le_out^T   [B*S, L]
    gemm(stream, 0, true, doc_n, DD, le_out, DD, nullptr, wla, LL, BB * SS, LL, DD);
    // 14. conv + channel/width max + tanh -> gate [B*S]
    conv_max_k<<<BB * SS, 256, 0, stream>>>(wla, conv_w, conv_b, gatev);
    // 15. h_enc[b,d] = sum_s gate*doc_n
    henc_k<<<(BB * DD + 255) / 256, 256, 0, stream>>>(doc_n, gatev, h_enc);
    // 16. label_output = sigmoid(h_enc @ w_lin1 + b_lin1)
    final_k<<<BB, 256, 0, stream>>>(h_enc, w_lin1, b_lin1, out);
    // 17. loss
    loss_k<<<1, 256, 0, stream>>>(out, labels, out + BB * LL);
}

// Round 2
// 1217.080 us; speedup vs baseline: 1.5512x; 1.5512x over previous
//
#include <hip/hip_runtime.h>
#include <hip/hip_bf16.h>
#include <math.h>

// Problem constants
#define BB 8
#define SS 512
#define DD 768
#define LL 200

typedef __attribute__((ext_vector_type(8))) short bf16x8;
typedef __attribute__((ext_vector_type(4))) float f32x4;

__device__ inline short f2bf(float f) {
    unsigned u = __builtin_bit_cast(unsigned, f);
    unsigned r = (u + 0x7FFFu + ((u >> 16) & 1u)) >> 16;
    return (short)r;
}

// ---------------------------------------------------------------------------
// Generic tiled fp32 GEMM: C[M,N] = epi(A[M,K] @ op(B) + bias)
// EPI: 0=none, 1=leaky(0.2), 2=sigmoid.  TB: B is [N,K] (use B^T).
// ---------------------------------------------------------------------------
#define BM 64
#define BN 64
#define BKK 16

template<int EPI, bool TB>
__global__ __launch_bounds__(256) void gemm_k(
    const float* __restrict__ A, int lda,
    const float* __restrict__ B, int ldb,
    const float* __restrict__ bias,
    float* __restrict__ C, int ldc,
    int M, int N, int K)
{
    __shared__ float As[BKK][BM + 4];
    __shared__ float Bs[BKK][BN + 4];
    const int tid = threadIdx.x;
    const int bm = blockIdx.y * BM;
    const int bn = blockIdx.x * BN;
    const int tx = tid & 15;   // -> 4 cols
    const int ty = tid >> 4;   // -> 4 rows

    float acc[4][4] = {};

    for (int k0 = 0; k0 < K; k0 += BKK) {
        for (int idx = tid; idx < BM * BKK; idx += 256) {
            int m = idx >> 4, kk = idx & 15;
            int gm = bm + m, gk = k0 + kk;
            float v = 0.f;
            if (gm < M && gk < K) v = A[(size_t)gm * lda + gk];
            As[kk][m] = v;
        }
        if (!TB) {
            for (int idx = tid; idx < BKK * BN; idx += 256) {
                int kk = idx >> 6, n = idx & 63;
                int gn = bn + n, gk = k0 + kk;
                float v = 0.f;
                if (gn < N && gk < K) v = B[(size_t)gk * ldb + gn];
                Bs[kk][n] = v;
            }
        } else {
            for (int idx = tid; idx < BKK * BN; idx += 256) {
                int n = idx >> 4, kk = idx & 15;
                int gn = bn + n, gk = k0 + kk;
                float v = 0.f;
                if (gn < N && gk < K) v = B[(size_t)gn * ldb + gk];
                Bs[kk][n] = v;
            }
        }
        __syncthreads();
        #pragma unroll
        for (int kk = 0; kk < BKK; ++kk) {
            float a[4], bb[4];
            #pragma unroll
            for (int i = 0; i < 4; ++i) a[i] = As[kk][ty * 4 + i];
            #pragma unroll
            for (int j = 0; j < 4; ++j) bb[j] = Bs[kk][tx * 4 + j];
            #pragma unroll
            for (int i = 0; i < 4; ++i)
                #pragma unroll
                for (int j = 0; j < 4; ++j)
                    acc[i][j] = fmaf(a[i], bb[j], acc[i][j]);
        }
        __syncthreads();
    }

    #pragma unroll
    for (int i = 0; i < 4; ++i) {
        int gm = bm + ty * 4 + i;
        if (gm >= M) continue;
        #pragma unroll
        for (int j = 0; j < 4; ++j) {
            int gn = bn + tx * 4 + j;
            if (gn >= N) continue;
            float v = acc[i][j];
            if (bias) v += bias[gn];
            if (EPI == 1) v = (v >= 0.f) ? v : 0.2f * v;
            else if (EPI == 2) v = 1.f / (1.f + expf(-v));
            C[(size_t)gm * ldc + gn] = v;
        }
    }
}

// d[m] = rsqrt(sum_l A[l,m]) (column sums of A [L,L])
__global__ void colsum_rsqrt_k(const float* __restrict__ A, float* __restrict__ d)
{
    int m = blockIdx.x * blockDim.x + threadIdx.x;
    if (m < LL) {
        float s = 0.f;
        for (int l = 0; l < LL; ++l) s += A[l * LL + m];
        d[m] = (s > 0.f) ? (1.f / sqrtf(s)) : 0.f;
    }
}

// A_norm[i,j] = A[j,i] * d[i] * d[j]
__global__ void anorm_k(const float* __restrict__ A, const float* __restrict__ d,
                        float* __restrict__ An)
{
    int idx = blockIdx.x * blockDim.x + threadIdx.x;
    if (idx < LL * LL) {
        int i = idx / LL, j = idx % LL;
        An[idx] = A[j * LL + i] * d[i] * d[j];
    }
}

// l1-normalize columns of X [L, D] in place (axis = L)
__global__ void l1norm_cols_k(float* __restrict__ X)
{
    int dcol = blockIdx.x * blockDim.x + threadIdx.x;
    if (dcol < DD) {
        float s = 0.f;
        for (int l = 0; l < LL; ++l) s += fabsf(X[l * DD + dcol]);
        float inv = 1.f / fmaxf(s, 1e-12f);
        for (int l = 0; l < LL; ++l) X[l * DD + dcol] *= inv;
    }
}

// doc_n[b,s,d] = doc[b,s,d] / max(sum_s |doc[b,s,d]|, 1e-12)
__global__ void doc_l1norm_k(const float* __restrict__ doc, float* __restrict__ out)
{
    int idx = blockIdx.x * blockDim.x + threadIdx.x;  // b*DD + d
    if (idx >= BB * DD) return;
    int b = idx / DD, dcol = idx % DD;
    const float* p = doc + (size_t)b * SS * DD + dcol;
    float s = 0.f;
    for (int t = 0; t < SS; ++t) s += fabsf(p[(size_t)t * DD]);
    float inv = 1.f / fmaxf(s, 1e-12f);
    float* q = out + (size_t)b * SS * DD + dcol;
    for (int t = 0; t < SS; ++t) q[(size_t)t * DD] = p[(size_t)t * DD] * inv;
}

// ---------------------------------------------------------------------------
// Prep: conv weights [200,81] f32 -> padded bf16 [208, 104] (row-major)
// ---------------------------------------------------------------------------
#define WK 104   // padded K stride (bf16 elems); 208 bytes -> odd 16B-chunk stride
__global__ void prep_wbf_k(const float* __restrict__ cw, short* __restrict__ wbf)
{
    int idx = blockIdx.x * blockDim.x + threadIdx.x;
    if (idx >= 208 * WK) return;
    int m = idx / WK, kk = idx % WK;
    float v = (m < LL && kk < 81) ? cw[m * 81 + kk] : 0.f;
    wbf[idx] = f2bf(v);
}

// ---------------------------------------------------------------------------
// Fused conv(9x9,200ch)+bias -> max over (channel,width) -> tanh, per (b,s),
// as an MFMA GEMM:  C[o,l] = sum_t W[o,t] * P[t,l],  t = i*9+j (K=81 pad 96)
//   P[t,l] = win[i][l+j]   (win = zero-padded 9x216 raw window, f32 in LDS)
// C-tile max-reduced immediately; never materialized.
// ---------------------------------------------------------------------------
__global__ __launch_bounds__(256, 3) void conv_max_k(
    const float* __restrict__ wla,   // [B*S, L]
    const short* __restrict__ wbf,   // [208, WK] bf16
    const float* __restrict__ cb,    // [L]
    float* __restrict__ gate)        // [B*S]
{
    __shared__ __align__(16) short Wlds[208 * WK];   // 43264 B
    __shared__ float win[9][216];                    // 7776 B
    __shared__ float cb_lds[208];
    __shared__ float wred[4];

    const int bs = blockIdx.x;
    const int b = bs >> 9;
    const int s = bs & 511;
    const int tid = threadIdx.x;
    const int w = tid >> 6;        // wave 0..3
    const int lane = tid & 63;
    const int g = lane >> 4;       // k-group 0..3
    const int ln = lane & 15;      // row/col-in-tile

    // stage W (bf16, pre-padded) via 16B copies
    {
        const int4* src = (const int4*)wbf;
        int4* dst = (int4*)Wlds;
        for (int i = tid; i < 208 * WK * 2 / 16; i += 256) dst[i] = src[i];
    }
    // stage raw window rows s-4..s+4, cols -4..211 (zero padded)
    for (int idx = tid; idx < 9 * 216; idx += 256) {
        int i = idx / 216, c = idx % 216;
        int row = s - 4 + i;
        int col = c - 4;
        float v = 0.f;
        if (row >= 0 && row < SS && col >= 0 && col < LL)
            v = wla[((size_t)b * SS + row) * LL + col];
        win[i][c] = v;
    }
    if (tid < 208) cb_lds[tid] = (tid < LL) ? cb[tid] : 0.f;
    __syncthreads();

    // Build B-fragments for this wave's ni columns: ni = w + 4*nb (<=12)
    // B[k][n] frag: lane (g,ln) holds k = ks*32 + g*8 + e at n = ni*16+ln
    bf16x8 Bf[4][3];
    #pragma unroll
    for (int nb = 0; nb < 4; ++nb) {
        int ni = w + nb * 4;
        bool nival = (ni <= 12);
        int n = ni * 16 + ln;
        #pragma unroll
        for (int ks = 0; ks < 3; ++ks) {
            bf16x8 f;
            #pragma unroll
            for (int e = 0; e < 8; ++e) {
                int t = ks * 32 + g * 8 + e;
                float v = 0.f;
                if (nival && t < 81) v = win[t / 9][n + (t % 9)];
                f[e] = f2bf(v);
            }
            Bf[nb][ks] = f;
        }
    }

    float vmax = -INFINITY;
    for (int mi = 0; mi < 13; ++mi) {
        // A-frags: W row-major; lane holds W[mi*16+ln][ks*32 + g*8 + 0..7]
        const bf16x8* ap = (const bf16x8*)(Wlds + (mi * 16 + ln) * WK);
        bf16x8 a0 = ap[0 + g];
        bf16x8 a1 = ap[4 + g];
        bf16x8 a2 = ap[8 + g];
        float cbv[4];
        #pragma unroll
        for (int r = 0; r < 4; ++r) cbv[r] = cb_lds[mi * 16 + g * 4 + r];

        #pragma unroll
        for (int nb = 0; nb < 4; ++nb) {
            int ni = w + nb * 4;
            if (ni > 12) continue;   // wave-uniform
            f32x4 acc = {0.f, 0.f, 0.f, 0.f};
            acc = __builtin_amdgcn_mfma_f32_16x16x32_bf16(a0, Bf[nb][0], acc, 0, 0, 0);
            acc = __builtin_amdgcn_mfma_f32_16x16x32_bf16(a1, Bf[nb][1], acc, 0, 0, 0);
            acc = __builtin_amdgcn_mfma_f32_16x16x32_bf16(a2, Bf[nb][2], acc, 0, 0, 0);
            int n = ni * 16 + ln;
            #pragma unroll
            for (int r = 0; r < 4; ++r) {
                int o = mi * 16 + g * 4 + r;     // C row = (lane>>4)*4 + reg
                float val = acc[r] + cbv[r];
                if (o < LL && n < LL) vmax = fmaxf(vmax, val);
            }
        }
    }

    #pragma unroll
    for (int off = 32; off > 0; off >>= 1)
        vmax = fmaxf(vmax, __shfl_down(vmax, off, 64));
    if (lane == 0) wred[w] = vmax;
    __syncthreads();
    if (tid == 0)
        gate[bs] = tanhf(fmaxf(fmaxf(wred[0], wred[1]), fmaxf(wred[2], wred[3])));
}

// h[b,d] = sum_s gate[b,s] * doc_n[b,s,d]
__global__ void henc_k(const float* __restrict__ doc_n, const float* __restrict__ gate,
                       float* __restrict__ h)
{
    int idx = blockIdx.x * blockDim.x + threadIdx.x;  // b*DD + d
    if (idx >= BB * DD) return;
    int b = idx / DD, dcol = idx % DD;
    const float* p = doc_n + (size_t)b * SS * DD + dcol;
    const float* g = gate + b * SS;
    float s = 0.f;
    for (int t = 0; t < SS; ++t) s = fmaf(p[(size_t)t * DD], g[t], s);
    h[idx] = s;
}

// out[b,l] = sigmoid(h[b,:] @ W[:,l] + bias[l])
__global__ void final_k(const float* __restrict__ h, const float* __restrict__ W,
                        const float* __restrict__ bias, float* __restrict__ out)
{
    int b = blockIdx.x;
    int l = threadIdx.x;
    if (l < LL) {
        const float* hb = h + b * DD;
        float acc = bias[l];
        for (int d = 0; d < DD; ++d) acc = fmaf(hb[d], W[d * LL + l], acc);
        out[b * LL + l] = 1.f / (1.f + expf(-acc));
    }
}

// loss = -mean(y*log(p) + (1-y)*log(1-p)), p clipped to [1e-7, 1-1e-7]
__global__ void loss_k(const float* __restrict__ out, const float* __restrict__ labels,
                       float* __restrict__ loss_out)
{
    float s = 0.f;
    for (int i = threadIdx.x; i < BB * LL; i += 256) {
        float p = out[i];
        p = fminf(fmaxf(p, 1e-7f), 1.f - 1e-7f);
        float y = labels[i];
        s += y * logf(p) + (1.f - y) * logf(1.f - p);
    }
    #pragma unroll
    for (int off = 32; off > 0; off >>= 1) s += __shfl_down(s, off, 64);
    __shared__ float ws[4];
    if ((threadIdx.x & 63) == 0) ws[threadIdx.x >> 6] = s;
    __syncthreads();
    if (threadIdx.x == 0)
        loss_out[0] = -(ws[0] + ws[1] + ws[2] + ws[3]) / (float)(BB * LL);
}

// ---------------------------------------------------------------------------
static void gemm(hipStream_t st, int epi, bool tb,
                 const float* A, int lda, const float* B, int ldb,
                 const float* bias, float* C, int ldc, int M, int N, int K)
{
    dim3 g((N + BN - 1) / BN, (M + BM - 1) / BM);
    if (!tb) {
        if (epi == 0)      gemm_k<0, false><<<g, 256, 0, st>>>(A, lda, B, ldb, bias, C, ldc, M, N, K);
        else if (epi == 1) gemm_k<1, false><<<g, 256, 0, st>>>(A, lda, B, ldb, bias, C, ldc, M, N, K);
        else               gemm_k<2, false><<<g, 256, 0, st>>>(A, lda, B, ldb, bias, C, ldc, M, N, K);
    } else {
        if (epi == 0)      gemm_k<0, true><<<g, 256, 0, st>>>(A, lda, B, ldb, bias, C, ldc, M, N, K);
        else if (epi == 1) gemm_k<1, true><<<g, 256, 0, st>>>(A, lda, B, ldb, bias, C, ldc, M, N, K);
        else               gemm_k<2, true><<<g, 256, 0, st>>>(A, lda, B, ldb, bias, C, ldc, M, N, K);
    }
}

extern "C" void kernel_launch(void* const* d_in, const int* in_sizes, int n_in,
                              void* d_out, int out_size, void* d_ws, size_t ws_size,
                              hipStream_t stream)
{
    const float* doc_emb   = (const float*)d_in[0];
    const float* labels    = (const float*)d_in[1];
    const float* label_emb = (const float*)d_in[2];
    const float* label_adj = (const float*)d_in[3];
    const float* w_gcn3    = (const float*)d_in[4];
    const float* w_gcn5    = (const float*)d_in[5];
    const float* w_ll1     = (const float*)d_in[6];
    const float* b_ll1     = (const float*)d_in[7];
    const float* w_ll2     = (const float*)d_in[8];
    const float* b_ll2     = (const float*)d_in[9];
    const float* w_lin     = (const float*)d_in[10];
    const float* b_lin     = (const float*)d_in[11];
    const float* conv_w    = (const float*)d_in[12];
    const float* conv_b    = (const float*)d_in[13];
    const float* w_lin1    = (const float*)d_in[14];
    const float* b_lin1    = (const float*)d_in[15];

    float* out = (float*)d_out;                       // [B*L] + [1]
    float* ws  = (float*)d_ws;

    // workspace layout (floats)
    float* le_cat = ws;                        // [L, 2D] (le | d_le)
    float* tmp    = le_cat + LL * 2 * DD;      // [L, D]
    float* q      = tmp + LL * DD;             // [L, D]
    float* k      = q + LL * DD;               // [L, D]
    float* Amat   = k + LL * DD;               // [L, L]
    float* dvec   = Amat + LL * LL;            // [256]
    float* Anorm  = dvec + 256;                // [L, L]
    float* le_out = Anorm + LL * LL;           // [L, D]
    float* doc_n  = le_out + LL * DD;          // [B, S, D]
    float* wla    = doc_n + (size_t)BB * SS * DD;  // [B*S, L]
    float* gatev  = wla + (size_t)BB * SS * LL;    // [B*S]
    float* h_enc  = gatev + BB * SS;           // [B, D]
    short* wbf    = (short*)(h_enc + BB * DD); // [208, WK] bf16

    // 0. conv weights -> padded bf16 (tiny)
    prep_wbf_k<<<(208 * WK + 255) / 256, 256, 0, stream>>>(conv_w, wbf);
    // 1. tmp = label_emb @ w_gcn3
    gemm(stream, 0, false, label_emb, DD, w_gcn3, DD, nullptr, tmp, DD, LL, DD, DD);
    // 2. le = leaky(label_adj @ tmp)
    gemm(stream, 1, false, label_adj, LL, tmp, DD, nullptr, le_cat, 2 * DD, LL, DD, LL);
    // 3. q = le @ w_ll1 + b_ll1
    gemm(stream, 0, false, le_cat, 2 * DD, w_ll1, DD, b_ll1, q, DD, LL, DD, DD);
    // 4. k = le @ w_ll2 + b_ll2
    gemm(stream, 0, false, le_cat, 2 * DD, w_ll2, DD, b_ll2, k, DD, LL, DD, DD);
    // 5. A = sigmoid(q @ k^T)
    gemm(stream, 2, true, q, DD, k, DD, nullptr, Amat, LL, LL, LL, DD);
    // 6. d = rsqrt(colsum(A))
    colsum_rsqrt_k<<<1, 256, 0, stream>>>(Amat, dvec);
    // 7. A_norm
    anorm_k<<<(LL * LL + 255) / 256, 256, 0, stream>>>(Amat, dvec, Anorm);
    // 8. tmp = le @ w_gcn5
    gemm(stream, 0, false, le_cat, 2 * DD, w_gcn5, DD, nullptr, tmp, DD, LL, DD, DD);
    // 9. d_le = leaky(A_norm @ tmp)
    gemm(stream, 1, false, Anorm, LL, tmp, DD, nullptr, le_cat + DD, 2 * DD, LL, DD, LL);
    // 10. le_out = le_cat @ w_lin + b_lin
    gemm(stream, 0, false, le_cat, 2 * DD, w_lin, DD, b_lin, le_out, DD, LL, DD, 2 * DD);
    // 11. l1 normalize le_out over L
    l1norm_cols_k<<<(DD + 255) / 256, 256, 0, stream>>>(le_out);
    // 12. doc l1 normalize over S
    doc_l1norm_k<<<(BB * DD + 255) / 256, 256, 0, stream>>>(doc_emb, doc_n);
    // 13. wla = doc_n @ le_out^T
    gemm(stream, 0, true, doc_n, DD, le_out, DD, nullptr, wla, LL, BB * SS, LL, DD);
    // 14. conv + max + tanh (MFMA)
    conv_max_k<<<BB * SS, 256, 0, stream>>>(wla, wbf, conv_b, gatev);
    // 15. h_enc
    henc_k<<<(BB * DD + 255) / 256, 256, 0, stream>>>(doc_n, gatev, h_enc);
    // 16. label_output
    final_k<<<BB, 256, 0, stream>>>(h_enc, w_lin1, b_lin1, out);
    // 17. loss
    loss_k<<<1, 256, 0, stream>>>(out, labels, out + BB * LL);
}

// Round 3
// 398.126 us; speedup vs baseline: 4.7421x; 3.0570x over previous
//
#include <hip/hip_runtime.h>
#include <hip/hip_bf16.h>
#include <math.h>

// Problem constants
#define BB 8
#define SS 512
#define DD 768
#define LL 200

typedef __attribute__((ext_vector_type(8))) short bf16x8;
typedef __attribute__((ext_vector_type(4))) float f32x4;

__device__ inline short f2bf(float f) {
    unsigned u = __builtin_bit_cast(unsigned, f);
    unsigned r = (u + 0x7FFFu + ((u >> 16) & 1u)) >> 16;
    return (short)r;
}

// ---------------------------------------------------------------------------
// MFMA bf16 GEMM: C[M,N] = epi(A_bf16[M,lda] @ B + bias)
//  - A: bf16 row-major, K contiguous, zero-padded to Kp (caller guarantees)
//  - TB=true : B is bf16 [N][ldb] row-major (K contiguous)  ("B^T layout")
//    TB=false: B is f32  [K][ldb] row-major (transposed+converted in staging)
//  - Cf (f32) and/or Cb (bf16) outputs, either may be null.
// Tile 64x64, K-step 32, 4 waves (wave w = 16 rows), register prefetch.
// ---------------------------------------------------------------------------
#define LDP 40   // LDS row pitch in bf16 elems (80 B = 5*16B -> 2-way max alias)

template<int EPI, bool TB>
__global__ __launch_bounds__(256) void mgemm_k(
    const short* __restrict__ A, int lda,
    const void* __restrict__ Bv, int ldb,
    const float* __restrict__ bias,
    float* __restrict__ Cf, int ldc,
    short* __restrict__ Cb, int ldcb,
    int M, int N, int K)
{
    __shared__ __align__(16) short As[64 * LDP];
    __shared__ __align__(16) short Bs[64 * LDP];
    const int tid = threadIdx.x;
    const int bm = blockIdx.y * 64;
    const int bn = blockIdx.x * 64;
    const int w = tid >> 6, lane = tid & 63, g = lane >> 4, ln = lane & 15;
    const int Kp = (K + 31) & ~31;
    const int nt = Kp >> 5;

    // staging coords
    const int ar = tid >> 2, ac = tid & 3;   // A / B(TB): row 0..63, 16B chunk 0..3
    const int bkk = tid >> 3, bc = tid & 7;  // B(f32): k-row 0..31, 8-float chunk

    f32x4 acc[4];
    #pragma unroll
    for (int i = 0; i < 4; ++i) acc[i] = (f32x4){0.f, 0.f, 0.f, 0.f};

    bf16x8 aR = {0,0,0,0,0,0,0,0};
    bf16x8 bR = {0,0,0,0,0,0,0,0};
    float  bF[8] = {0,0,0,0,0,0,0,0};

    const int gmS = bm + ar;                 // staging row (A)
    const bool aOk = (gmS < M);

    // ---- prefetch tile 0 ----
    if (aOk) aR = *(const bf16x8*)(A + (size_t)gmS * lda + ac * 8);
    if (TB) {
        const short* Bt = (const short*)Bv;
        int gn = bn + ar;
        if (gn < N) bR = *(const bf16x8*)(Bt + (size_t)gn * ldb + ac * 8);
    } else {
        const float* Bp = (const float*)Bv;
        int gk = bkk;
        int n0 = bn + bc * 8;
        if (gk < K) {
            const float* p = Bp + (size_t)gk * ldb + n0;
            if (n0 + 8 <= N) {
                float4 x = *(const float4*)p, y = *(const float4*)(p + 4);
                bF[0]=x.x; bF[1]=x.y; bF[2]=x.z; bF[3]=x.w;
                bF[4]=y.x; bF[5]=y.y; bF[6]=y.z; bF[7]=y.w;
            } else {
                #pragma unroll
                for (int j = 0; j < 8; ++j) bF[j] = (n0 + j < N) ? p[j] : 0.f;
            }
        }
    }

    for (int t = 0; t < nt; ++t) {
        // ---- write staged tile to LDS ----
        *(bf16x8*)(As + ar * LDP + ac * 8) = aR;
        if (TB) {
            *(bf16x8*)(Bs + ar * LDP + ac * 8) = bR;
        } else {
            #pragma unroll
            for (int j = 0; j < 8; ++j)
                Bs[(bc * 8 + j) * LDP + bkk] = f2bf(bF[j]);
        }
        __syncthreads();

        // ---- prefetch tile t+1 ----
        if (t + 1 < nt) {
            int k0 = (t + 1) << 5;
            if (aOk) aR = *(const bf16x8*)(A + (size_t)gmS * lda + k0 + ac * 8);
            if (TB) {
                const short* Bt = (const short*)Bv;
                int gn = bn + ar;
                if (gn < N) bR = *(const bf16x8*)(Bt + (size_t)gn * ldb + k0 + ac * 8);
            } else {
                const float* Bp = (const float*)Bv;
                int gk = k0 + bkk;
                int n0 = bn + bc * 8;
                if (gk < K) {
                    const float* p = Bp + (size_t)gk * ldb + n0;
                    if (n0 + 8 <= N) {
                        float4 x = *(const float4*)p, y = *(const float4*)(p + 4);
                        bF[0]=x.x; bF[1]=x.y; bF[2]=x.z; bF[3]=x.w;
                        bF[4]=y.x; bF[5]=y.y; bF[6]=y.z; bF[7]=y.w;
                    } else {
                        #pragma unroll
                        for (int j = 0; j < 8; ++j) bF[j] = (n0 + j < N) ? p[j] : 0.f;
                    }
                } else {
                    #pragma unroll
                    for (int j = 0; j < 8; ++j) bF[j] = 0.f;
                }
            }
        }

        // ---- compute ----
        bf16x8 a = *(const bf16x8*)(As + (w * 16 + ln) * LDP + g * 8);
        #pragma unroll
        for (int nb = 0; nb < 4; ++nb) {
            bf16x8 b = *(const bf16x8*)(Bs + (nb * 16 + ln) * LDP + g * 8);
            acc[nb] = __builtin_amdgcn_mfma_f32_16x16x32_bf16(a, b, acc[nb], 0, 0, 0);
        }
        __syncthreads();
    }

    // ---- epilogue: C row = (lane>>4)*4 + reg, col = lane&15  (verified map) ----
    #pragma unroll
    for (int nb = 0; nb < 4; ++nb) {
        int gn = bn + nb * 16 + ln;
        float bv = (bias && gn < N) ? bias[gn] : 0.f;
        #pragma unroll
        for (int r = 0; r < 4; ++r) {
            int gm = bm + w * 16 + g * 4 + r;
            if (gm < M && gn < N) {
                float v = acc[nb][r] + bv;
                if (EPI == 1) v = (v >= 0.f) ? v : 0.2f * v;
                else if (EPI == 2) v = 1.f / (1.f + expf(-v));
                if (Cf) Cf[(size_t)gm * ldc + gn] = v;
                if (Cb) Cb[(size_t)gm * ldcb + gn] = f2bf(v);
            }
        }
    }
}

// ---------------------------------------------------------------------------
// small helpers
// ---------------------------------------------------------------------------
// f32 [R,C] -> bf16 [R,Cp] zero-padded
__global__ void pad_bf_k(const float* __restrict__ src, short* __restrict__ dst,
                         int R, int C, int Cp)
{
    int idx = blockIdx.x * blockDim.x + threadIdx.x;
    if (idx >= R * Cp) return;
    int r = idx / Cp, c = idx % Cp;
    dst[idx] = f2bf(c < C ? src[r * C + c] : 0.f);
}

// d[m] = rsqrt(sum_l A[l,m]) (column sums of A [L,L])
__global__ void colsum_rsqrt_k(const float* __restrict__ A, float* __restrict__ d)
{
    int m = blockIdx.x * blockDim.x + threadIdx.x;
    if (m < LL) {
        float s = 0.f;
        for (int l = 0; l < LL; ++l) s += A[l * LL + m];
        d[m] = (s > 0.f) ? (1.f / sqrtf(s)) : 0.f;
    }
}

// Anorm_bf[i][j] = bf16( A[j,i] * d[i] * d[j] ), padded [200][224]
__global__ void anorm_bf_k(const float* __restrict__ A, const float* __restrict__ d,
                           short* __restrict__ An)
{
    int idx = blockIdx.x * blockDim.x + threadIdx.x;
    if (idx >= LL * 224) return;
    int i = idx / 224, j = idx % 224;
    float v = (j < LL) ? A[j * LL + i] * d[i] * d[j] : 0.f;
    An[idx] = f2bf(v);
}

// l1-normalize columns of X [L,D] (axis=L), emit bf16 [L,D]
__global__ void l1norm_cols_bf_k(const float* __restrict__ X, short* __restrict__ Xb)
{
    int dcol = blockIdx.x * blockDim.x + threadIdx.x;
    if (dcol >= DD) return;
    float s = 0.f;
    for (int l = 0; l < LL; ++l) s += fabsf(X[l * DD + dcol]);
    float inv = 1.f / fmaxf(s, 1e-12f);
    for (int l = 0; l < LL; ++l) Xb[l * DD + dcol] = f2bf(X[l * DD + dcol] * inv);
}

// doc l1-norm over S: emit bf16 normalized doc + denom[b,d]
__global__ void doc_l1norm2_k(const float* __restrict__ doc, short* __restrict__ docb,
                              float* __restrict__ denom)
{
    int idx = blockIdx.x * blockDim.x + threadIdx.x;  // b*DD + d
    if (idx >= BB * DD) return;
    int b = idx / DD, dcol = idx % DD;
    const float* p = doc + (size_t)b * SS * DD + dcol;
    float s = 0.f;
    for (int t = 0; t < SS; ++t) s += fabsf(p[(size_t)t * DD]);
    s = fmaxf(s, 1e-12f);
    denom[idx] = s;
    float inv = 1.f / s;
    short* q = docb + (size_t)b * SS * DD + dcol;
    for (int t = 0; t < SS; ++t) q[(size_t)t * DD] = f2bf(p[(size_t)t * DD] * inv);
}

// ---------------------------------------------------------------------------
// Conv weights [200,81] f32 -> padded bf16 [208, 104]
// ---------------------------------------------------------------------------
#define WK 104
__global__ void prep_wbf_k(const float* __restrict__ cw, short* __restrict__ wbf)
{
    int idx = blockIdx.x * blockDim.x + threadIdx.x;
    if (idx >= 208 * WK) return;
    int m = idx / WK, kk = idx % WK;
    float v = (m < LL && kk < 81) ? cw[m * 81 + kk] : 0.f;
    wbf[idx] = f2bf(v);
}

// ---------------------------------------------------------------------------
// Fused conv(9x9,200ch)+bias -> max over (channel,width) -> tanh, per (b,s)
// (MFMA formulation, unchanged from round 1 — verified)
// ---------------------------------------------------------------------------
__global__ __launch_bounds__(256, 3) void conv_max_k(
    const float* __restrict__ wla,   // [B*S, L]
    const short* __restrict__ wbf,   // [208, WK] bf16
    const float* __restrict__ cb,    // [L]
    float* __restrict__ gate)        // [B*S]
{
    __shared__ __align__(16) short Wlds[208 * WK];
    __shared__ float win[9][216];
    __shared__ float cb_lds[208];
    __shared__ float wred[4];

    const int bs = blockIdx.x;
    const int b = bs >> 9;
    const int s = bs & 511;
    const int tid = threadIdx.x;
    const int w = tid >> 6;
    const int lane = tid & 63;
    const int g = lane >> 4;
    const int ln = lane & 15;

    {
        const int4* src = (const int4*)wbf;
        int4* dst = (int4*)Wlds;
        for (int i = tid; i < 208 * WK * 2 / 16; i += 256) dst[i] = src[i];
    }
    for (int idx = tid; idx < 9 * 216; idx += 256) {
        int i = idx / 216, c = idx % 216;
        int row = s - 4 + i;
        int col = c - 4;
        float v = 0.f;
        if (row >= 0 && row < SS && col >= 0 && col < LL)
            v = wla[((size_t)b * SS + row) * LL + col];
        win[i][c] = v;
    }
    if (tid < 208) cb_lds[tid] = (tid < LL) ? cb[tid] : 0.f;
    __syncthreads();

    bf16x8 Bf[4][3];
    #pragma unroll
    for (int nb = 0; nb < 4; ++nb) {
        int ni = w + nb * 4;
        bool nival = (ni <= 12);
        int n = ni * 16 + ln;
        #pragma unroll
        for (int ks = 0; ks < 3; ++ks) {
            bf16x8 f;
            #pragma unroll
            for (int e = 0; e < 8; ++e) {
                int t = ks * 32 + g * 8 + e;
                float v = 0.f;
                if (nival && t < 81) v = win[t / 9][n + (t % 9)];
                f[e] = f2bf(v);
            }
            Bf[nb][ks] = f;
        }
    }

    float vmax = -INFINITY;
    for (int mi = 0; mi < 13; ++mi) {
        const bf16x8* ap = (const bf16x8*)(Wlds + (mi * 16 + ln) * WK);
        bf16x8 a0 = ap[0 + g];
        bf16x8 a1 = ap[4 + g];
        bf16x8 a2 = ap[8 + g];
        float cbv[4];
        #pragma unroll
        for (int r = 0; r < 4; ++r) cbv[r] = cb_lds[mi * 16 + g * 4 + r];

        #pragma unroll
        for (int nb = 0; nb < 4; ++nb) {
            int ni = w + nb * 4;
            if (ni > 12) continue;
            f32x4 acc = {0.f, 0.f, 0.f, 0.f};
            acc = __builtin_amdgcn_mfma_f32_16x16x32_bf16(a0, Bf[nb][0], acc, 0, 0, 0);
            acc = __builtin_amdgcn_mfma_f32_16x16x32_bf16(a1, Bf[nb][1], acc, 0, 0, 0);
            acc = __builtin_amdgcn_mfma_f32_16x16x32_bf16(a2, Bf[nb][2], acc, 0, 0, 0);
            int n = ni * 16 + ln;
            #pragma unroll
            for (int r = 0; r < 4; ++r) {
                int o = mi * 16 + g * 4 + r;
                float val = acc[r] + cbv[r];
                if (o < LL && n < LL) vmax = fmaxf(vmax, val);
            }
        }
    }

    #pragma unroll
    for (int off = 32; off > 0; off >>= 1)
        vmax = fmaxf(vmax, __shfl_down(vmax, off, 64));
    if (lane == 0) wred[w] = vmax;
    __syncthreads();
    if (tid == 0)
        gate[bs] = tanhf(fmaxf(fmaxf(wred[0], wred[1]), fmaxf(wred[2], wred[3])));
}

// h[b,d] = (sum_s gate[b,s] * doc[b,s,d]) / denom[b,d]
__global__ void henc_k(const float* __restrict__ doc, const float* __restrict__ gate,
                       const float* __restrict__ denom, float* __restrict__ h)
{
    int idx = blockIdx.x * blockDim.x + threadIdx.x;
    if (idx >= BB * DD) return;
    int b = idx / DD, dcol = idx % DD;
    const float* p = doc + (size_t)b * SS * DD + dcol;
    const float* g = gate + b * SS;
    float s = 0.f;
    for (int t = 0; t < SS; ++t) s = fmaf(p[(size_t)t * DD], g[t], s);
    h[idx] = s / denom[idx];
}

// out[b,l] = sigmoid(h[b,:] @ W[:,l] + bias[l])
__global__ void final_k(const float* __restrict__ h, const float* __restrict__ W,
                        const float* __restrict__ bias, float* __restrict__ out)
{
    int b = blockIdx.x;
    int l = threadIdx.x;
    if (l < LL) {
        const float* hb = h + b * DD;
        float acc = bias[l];
        for (int d = 0; d < DD; ++d) acc = fmaf(hb[d], W[d * LL + l], acc);
        out[b * LL + l] = 1.f / (1.f + expf(-acc));
    }
}

__global__ void loss_k(const float* __restrict__ out, const float* __restrict__ labels,
                       float* __restrict__ loss_out)
{
    float s = 0.f;
    for (int i = threadIdx.x; i < BB * LL; i += 256) {
        float p = out[i];
        p = fminf(fmaxf(p, 1e-7f), 1.f - 1e-7f);
        float y = labels[i];
        s += y * logf(p) + (1.f - y) * logf(1.f - p);
    }
    #pragma unroll
    for (int off = 32; off > 0; off >>= 1) s += __shfl_down(s, off, 64);
    __shared__ float ws[4];
    if ((threadIdx.x & 63) == 0) ws[threadIdx.x >> 6] = s;
    __syncthreads();
    if (threadIdx.x == 0)
        loss_out[0] = -(ws[0] + ws[1] + ws[2] + ws[3]) / (float)(BB * LL);
}

// ---------------------------------------------------------------------------
static void mgemm(hipStream_t st, int epi, bool tb,
                  const short* A, int lda, const void* B, int ldb,
                  const float* bias, float* Cf, int ldc, short* Cb, int ldcb,
                  int M, int N, int K)
{
    dim3 g((N + 63) / 64, (M + 63) / 64);
    if (!tb) {
        if (epi == 0)      mgemm_k<0, false><<<g, 256, 0, st>>>(A, lda, B, ldb, bias, Cf, ldc, Cb, ldcb, M, N, K);
        else if (epi == 1) mgemm_k<1, false><<<g, 256, 0, st>>>(A, lda, B, ldb, bias, Cf, ldc, Cb, ldcb, M, N, K);
        else               mgemm_k<2, false><<<g, 256, 0, st>>>(A, lda, B, ldb, bias, Cf, ldc, Cb, ldcb, M, N, K);
    } else {
        if (epi == 0)      mgemm_k<0, true><<<g, 256, 0, st>>>(A, lda, B, ldb, bias, Cf, ldc, Cb, ldcb, M, N, K);
        else if (epi == 1) mgemm_k<1, true><<<g, 256, 0, st>>>(A, lda, B, ldb, bias, Cf, ldc, Cb, ldcb, M, N, K);
        else               mgemm_k<2, true><<<g, 256, 0, st>>>(A, lda, B, ldb, bias, Cf, ldc, Cb, ldcb, M, N, K);
    }
}

extern "C" void kernel_launch(void* const* d_in, const int* in_sizes, int n_in,
                              void* d_out, int out_size, void* d_ws, size_t ws_size,
                              hipStream_t stream)
{
    const float* doc_emb   = (const float*)d_in[0];
    const float* labels    = (const float*)d_in[1];
    const float* label_emb = (const float*)d_in[2];
    const float* label_adj = (const float*)d_in[3];
    const float* w_gcn3    = (const float*)d_in[4];
    const float* w_gcn5    = (const float*)d_in[5];
    const float* w_ll1     = (const float*)d_in[6];
    const float* b_ll1     = (const float*)d_in[7];
    const float* w_ll2     = (const float*)d_in[8];
    const float* b_ll2     = (const float*)d_in[9];
    const float* w_lin     = (const float*)d_in[10];
    const float* b_lin     = (const float*)d_in[11];
    const float* conv_w    = (const float*)d_in[12];
    const float* conv_b    = (const float*)d_in[13];
    const float* w_lin1    = (const float*)d_in[14];
    const float* b_lin1    = (const float*)d_in[15];

    float* out = (float*)d_out;   // [B*L] + [1]

    // workspace carve-up (all blocks 16B aligned)
    char* p = (char*)d_ws;
    auto alloc = [&](size_t bytes) { void* r = p; p += (bytes + 15) & ~(size_t)15; return r; };
    short* adj_bf    = (short*)alloc(200 * 224 * 2);
    short* E2_bf     = (short*)alloc(200 * 768 * 2);
    float* le_f      = (float*)alloc(200 * 768 * 4);
    short* le_cat_bf = (short*)alloc(200 * 1536 * 2);   // [le | d_le]
    short* q_bf      = (short*)alloc(200 * 768 * 2);
    short* k_bf      = (short*)alloc(200 * 768 * 2);
    float* Amat      = (float*)alloc(200 * 200 * 4);
    float* dvec      = (float*)alloc(256 * 4);
    short* Anorm_bf  = (short*)alloc(200 * 224 * 2);
    short* G_bf      = (short*)alloc(200 * 768 * 2);
    float* le_out_f  = (float*)alloc(200 * 768 * 4);
    short* le_out_bf = (short*)alloc(200 * 768 * 2);
    float* denom     = (float*)alloc(BB * DD * 4);
    short* doc_nb    = (short*)alloc((size_t)BB * SS * DD * 2);
    float* wla       = (float*)alloc((size_t)BB * SS * LL * 4);
    float* gatev     = (float*)alloc(BB * SS * 4);
    float* h_enc     = (float*)alloc(BB * DD * 4);
    short* wbf       = (short*)alloc(208 * WK * 2);

    // prep
    prep_wbf_k<<<(208 * WK + 255) / 256, 256, 0, stream>>>(conv_w, wbf);
    pad_bf_k<<<(200 * 224 + 255) / 256, 256, 0, stream>>>(label_adj, adj_bf, 200, 200, 224);

    // E2 = adj @ emb                       [200,768], K=200
    mgemm(stream, 0, false, adj_bf, 224, label_emb, DD, nullptr,
          nullptr, 0, E2_bf, DD, LL, DD, LL);
    // le = leaky(E2 @ W3)  -> f32 + bf16 (into le_cat[:, :768])
    mgemm(stream, 1, false, E2_bf, DD, w_gcn3, DD, nullptr,
          le_f, DD, le_cat_bf, 1536, LL, DD, DD);
    // q = le @ w_ll1 + b1
    mgemm(stream, 0, false, le_cat_bf, 1536, w_ll1, DD, b_ll1,
          nullptr, 0, q_bf, DD, LL, DD, DD);
    // k = le @ w_ll2 + b2
    mgemm(stream, 0, false, le_cat_bf, 1536, w_ll2, DD, b_ll2,
          nullptr, 0, k_bf, DD, LL, DD, DD);
    // A = sigmoid(q @ k^T)                 [200,200]
    mgemm(stream, 2, true, q_bf, DD, k_bf, DD, nullptr,
          Amat, LL, nullptr, 0, LL, LL, DD);
    // degree vector + normalized adjacency (bf16, padded K=224)
    colsum_rsqrt_k<<<1, 256, 0, stream>>>(Amat, dvec);
    anorm_bf_k<<<(200 * 224 + 255) / 256, 256, 0, stream>>>(Amat, dvec, Anorm_bf);
    // G = Anorm @ le                       [200,768], K=200
    mgemm(stream, 0, false, Anorm_bf, 224, le_f, DD, nullptr,
          nullptr, 0, G_bf, DD, LL, DD, LL);
    // d_le = leaky(G @ W5) -> bf16 into le_cat[:, 768:]
    mgemm(stream, 1, false, G_bf, DD, w_gcn5, DD, nullptr,
          nullptr, 0, le_cat_bf + DD, 1536, LL, DD, DD);
    // le_out = le_cat @ w_lin + b_lin      [200,768], K=1536
    mgemm(stream, 0, false, le_cat_bf, 1536, w_lin, DD, b_lin,
          le_out_f, DD, nullptr, 0, LL, DD, 2 * DD);
    // l1 normalize over L -> bf16
    l1norm_cols_bf_k<<<(DD + 255) / 256, 256, 0, stream>>>(le_out_f, le_out_bf);
    // doc l1 normalize over S -> bf16 + denom
    doc_l1norm2_k<<<(BB * DD + 255) / 256, 256, 0, stream>>>(doc_emb, doc_nb, denom);
    // wla = doc_n @ le_out^T               [4096,200], K=768
    mgemm(stream, 0, true, doc_nb, DD, le_out_bf, DD, nullptr,
          wla, LL, nullptr, 0, BB * SS, LL, DD);
    // conv + max + tanh
    conv_max_k<<<BB * SS, 256, 0, stream>>>(wla, wbf, conv_b, gatev);
    // h_enc
    henc_k<<<(BB * DD + 255) / 256, 256, 0, stream>>>(doc_emb, gatev, denom, h_enc);
    // label_output
    final_k<<<BB, 256, 0, stream>>>(h_enc, w_lin1, b_lin1, out);
    // loss
    loss_k<<<1, 256, 0, stream>>>(out, labels, out + BB * LL);
}